// Round 9
// baseline (129.869 us; speedup 1.0000x reference)
//
#include <hip/hip_runtime.h>

// KMeans soft-assignment via bf16 hi/lo split MFMA (3 passes), fused softmax.
// logits = (2*x.c - ||c||^2)/T, T=0.1; ||x||^2 cancels in softmax.
// R19: 32x32x16 MFMA shape swap on the R17 skeleton (best, 47.0us).
// Serial-sum model from R10-R18: dur ~= MFMA 29.8k + LDS 24.6k + VALU ~20k
// cyc/CU summed serially; every overlap attack (occupancy R11/R13/R16,
// counted vmcnt R17, phase-split R18) was null or negative. So: shrink the
// biggest term. 32x32x16 = 4060 FLOP/cyc/CU vs 16x16x32's 3377 (m119):
// -17% MFMA cycles, -50% MFMA instruction count; ds_read count unchanged.
// B stored fragment-major for the 32x32 B operand (lane-linear 16B reads,
// conflict-free, swizzle-free). K-loop sync = R17 verbatim: counted
// vmcnt(4) -> s_barrier -> DMA-after-barrier; no sub-phase barriers (R18
// regression). C layout: col=lane&31, row=(reg&3)+8*(reg>>2)+4*(lane>>5).
// x: [32768,256] f32, c: [512,256] f32, out: [32768,512] f32
#define NROWS 32768
#define KC 512
#define DDIM 256
#define BM 128
#define BK 32
#define KCH (DDIM / BK)        // 8 k-chunks
#define CHUNK_USH (KC * BK)    // 16384 ushorts = 32 KB per chunk table

typedef __attribute__((ext_vector_type(8))) short bf16x8;
typedef __attribute__((ext_vector_type(16))) float f32x16;

union U8 { unsigned short u[8]; bf16x8 v; };

__device__ __forceinline__ unsigned short f2bf(float f) {   // RNE f32->bf16
    union { float f; unsigned int u; } a; a.f = f;
    unsigned int r = a.u + 0x7fffu + ((a.u >> 16) & 1u);
    return (unsigned short)(r >> 16);
}
__device__ __forceinline__ float bf2f(unsigned short h) {
    union { unsigned int u; float f; } a; a.u = ((unsigned int)h) << 16;
    return a.f;
}
// async global->LDS, 16B/lane; LDS dst must be wave-uniform base + lane*16
__device__ __forceinline__ void ld16(const void* g, void* l) {
    __builtin_amdgcn_global_load_lds(
        (const __attribute__((address_space(1))) unsigned int*)g,
        (__attribute__((address_space(3))) unsigned int*)l, 16, 0, 0);
}

// ---- prep: c -> fragment-major (32x32x16 B operand) bf16 hi/lo + csq10 ----
// Fragment (ks, T32, s): 32-col tile T32, k-halfstep s (K=16). 64 lanes x
// 8 ushorts (1 KB): lane l = col T32*32+(l&31), k = ks*32+s*16+(l>>5)*8+j.
__global__ __launch_bounds__(64) void prep_c(const float* __restrict__ c,
                                             unsigned short* __restrict__ bhi,
                                             unsigned short* __restrict__ blo,
                                             float* __restrict__ csq10) {
    const int n = blockIdx.x, lane = threadIdx.x;
    const int d0 = lane * 4;
    float4 v = ((const float4*)(c + (size_t)n * DDIM))[lane];
    float vv[4] = {v.x, v.y, v.z, v.w};
    unsigned short hh[4], ll[4];
    float ssq = 0.f;
    #pragma unroll
    for (int i = 0; i < 4; ++i) {
        ssq += vv[i] * vv[i];
        hh[i] = f2bf(vv[i]);
        ll[i] = f2bf(vv[i] - bf2f(hh[i]));
    }
    #pragma unroll
    for (int off = 32; off; off >>= 1) ssq += __shfl_xor(ssq, off);
    if (lane == 0) csq10[n] = 10.f * ssq;
    const int ks   = d0 >> 5;            // k-chunk
    const int s    = (d0 >> 4) & 1;      // k-halfstep within chunk
    const int half = (d0 >> 3) & 1;      // k-octet within halfstep
    const int e    = d0 & 7;
    const int T32  = n >> 5, c32 = n & 31;
    const size_t dst = (((size_t)ks * 16 + T32) * 2 + s) * 512
                     + (half * 32 + c32) * 8 + e;
    *(ushort4*)(bhi + dst) = make_ushort4(hh[0], hh[1], hh[2], hh[3]);
    *(ushort4*)(blo + dst) = make_ushort4(ll[0], ll[1], ll[2], ll[3]);
}

// ---- main: 256 blocks x 512 threads (8 waves = 4 M-groups x 2 N-halves) ----
union SmemU {
    struct { unsigned short Bh[2][CHUNK_USH], Bl[2][CHUNK_USH]; } k;  // 128 KB
    float lbuf[32 * 516];                                             // 66 KB overlay
};

__global__ __launch_bounds__(512, 2) void kmeans_mfma(
    const float* __restrict__ x, const unsigned short* __restrict__ bhi,
    const unsigned short* __restrict__ blo, const float* __restrict__ csq10,
    float* __restrict__ out) {
    __shared__ __align__(16) SmemU sm;
    __shared__ float red[2][2][BM];   // 2 KB

    const int tid  = threadIdx.x;
    const int w    = tid >> 6, lane = tid & 63;
    const int wm   = w >> 1, wn = w & 1;
    const int c32  = lane & 31, hi = lane >> 5;
    const int row0 = blockIdx.x * BM;

    f32x16 acc[8];
    #pragma unroll
    for (int t = 0; t < 8; ++t)
        #pragma unroll
        for (int g = 0; g < 16; ++g) acc[t][g] = 0.f;

    // A: lane owns row (row0 + wm*32 + c32), k-octet hi*8 within each halfstep
    const float* xA = x + (size_t)(row0 + wm * 32 + c32) * DDIM + hi * 8;
    // DMA slots: wave w, j=0..3 -> 1 KB segment (w*4+j)*512 ushorts
    const int dmaOff = (w * 4) * 512;

    // ---- prologue: issue A(0), then DMA chunk 0 -> buf 0 (no barrier yet) ----
    float4 c00 = *(const float4*)xA;            // s=0 octet
    float4 c01 = *(const float4*)(xA + 4);
    float4 c10 = *(const float4*)(xA + 16);     // s=1 octet
    float4 c11 = *(const float4*)(xA + 20);
    #pragma unroll
    for (int j = 0; j < 4; ++j) {
        const int o = dmaOff + j * 512;
        ld16(bhi + o + lane * 8, &sm.k.Bh[0][o]);
        ld16(blo + o + lane * 8, &sm.k.Bl[0][o]);
    }

    #pragma unroll
    for (int ks = 0; ks < KCH; ++ks) {
        const int pp = ks & 1;
        // convert A(ks): compiler-counted vmcnt (DMA(ks) ops younger)
        bf16x8 ah[2], al[2];
        {
            float v0[8] = {c00.x, c00.y, c00.z, c00.w, c01.x, c01.y, c01.z, c01.w};
            float v1[8] = {c10.x, c10.y, c10.z, c10.w, c11.x, c11.y, c11.z, c11.w};
            U8 H0, L0, H1, L1;
            #pragma unroll
            for (int e = 0; e < 8; ++e) {
                H0.u[e] = f2bf(v0[e]); L0.u[e] = f2bf(v0[e] - bf2f(H0.u[e]));
                H1.u[e] = f2bf(v1[e]); L1.u[e] = f2bf(v1[e] - bf2f(H1.u[e]));
            }
            ah[0] = H0.v; al[0] = L0.v; ah[1] = H1.v; al[1] = L1.v;
        }
        // issue A(ks+1) raw (youngest; stays in flight across the barrier)
        float4 n00, n01, n10, n11;
        if (ks < KCH - 1) {
            const int kn = (ks + 1) * BK;
            n00 = *(const float4*)(xA + kn);
            n01 = *(const float4*)(xA + kn + 4);
            n10 = *(const float4*)(xA + kn + 16);
            n11 = *(const float4*)(xA + kn + 20);
        }
        __builtin_amdgcn_sched_barrier(0);
        // counted wait: DMA(ks) complete; A(ks+1) (4 youngest) stays in flight
        if (ks < KCH - 1) {
            asm volatile("s_waitcnt vmcnt(4)" ::: "memory");
        } else {
            asm volatile("s_waitcnt vmcnt(0)" ::: "memory");
        }
        __builtin_amdgcn_s_barrier();
        __builtin_amdgcn_sched_barrier(0);
        // issue DMA(ks+1) into the other slot (safe only post-barrier)
        if (ks < KCH - 1) {
            const size_t cb = (size_t)(ks + 1) * CHUNK_USH;
            #pragma unroll
            for (int j = 0; j < 4; ++j) {
                const int o = dmaOff + j * 512;
                ld16(bhi + cb + o + lane * 8, &sm.k.Bh[1 - pp][o]);
                ld16(blo + cb + o + lane * 8, &sm.k.Bl[1 - pp][o]);
            }
        }
        // MFMA phase: 2 k-halfsteps x 2 groups of 4 tiles x 3 passes.
        // Per-element pass order h*h, h*l, l*h (R10/R17 convention).
        #pragma unroll
        for (int s = 0; s < 2; ++s)
            #pragma unroll
            for (int grp = 0; grp < 2; ++grp) {
                bf16x8 bh[4], bl[4];
                #pragma unroll
                for (int j = 0; j < 4; ++j) {
                    const int bo = ((wn * 8 + grp * 4 + j) * 2 + s) * 512 + lane * 8;
                    bh[j] = *(const bf16x8*)&sm.k.Bh[pp][bo];
                    bl[j] = *(const bf16x8*)&sm.k.Bl[pp][bo];
                }
                #pragma unroll
                for (int j = 0; j < 4; ++j)
                    acc[grp * 4 + j] = __builtin_amdgcn_mfma_f32_32x32x16_bf16(
                        ah[s], bh[j], acc[grp * 4 + j], 0, 0, 0);
                #pragma unroll
                for (int j = 0; j < 4; ++j)
                    acc[grp * 4 + j] = __builtin_amdgcn_mfma_f32_32x32x16_bf16(
                        ah[s], bl[j], acc[grp * 4 + j], 0, 0, 0);
                #pragma unroll
                for (int j = 0; j < 4; ++j)
                    acc[grp * 4 + j] = __builtin_amdgcn_mfma_f32_32x32x16_bf16(
                        al[s], bh[j], acc[grp * 4 + j], 0, 0, 0);
            }
        c00 = n00; c01 = n01; c10 = n10; c11 = n11;
    }

    // ---- softmax stats (32x32 C layout: col=lane&31, row=(g&3)+8*(g>>2)+4*hi)
    float csqv[8];
    #pragma unroll
    for (int t = 0; t < 8; ++t) csqv[t] = csq10[wn * 256 + t * 32 + c32];
    float M[16], I[16];
    #pragma unroll
    for (int g = 0; g < 16; ++g) {
        const int rg = (g & 3) + 8 * (g >> 2) + 4 * hi;   // row 0..31 in wm group
        float pm = -1e30f;
        #pragma unroll
        for (int t = 0; t < 8; ++t) pm = fmaxf(pm, fmaf(20.f, acc[t][g], -csqv[t]));
        #pragma unroll
        for (int off = 1; off < 32; off <<= 1) pm = fmaxf(pm, __shfl_xor(pm, off));
        if (c32 == 0) red[0][wn][wm * 32 + rg] = pm;
        M[g] = pm;
    }
    __syncthreads();
    #pragma unroll
    for (int g = 0; g < 16; ++g) {
        const int rg = (g & 3) + 8 * (g >> 2) + 4 * hi;
        const int ri = wm * 32 + rg;
        M[g] = fmaxf(M[g], red[0][1 - wn][ri]);
        float ps = 0.f;
        #pragma unroll
        for (int t = 0; t < 8; ++t) ps += __expf(fmaf(20.f, acc[t][g], -csqv[t]) - M[g]);
        #pragma unroll
        for (int off = 1; off < 32; off <<= 1) ps += __shfl_xor(ps, off);
        if (c32 == 0) red[1][wn][ri] = ps;
    }
    __syncthreads();
    #pragma unroll
    for (int g = 0; g < 16; ++g) {
        const int ri = wm * 32 + (g & 3) + 8 * (g >> 2) + 4 * hi;
        I[g] = 1.f / (red[1][0][ri] + red[1][1][ri]);
    }

    // ---- transpose epilogue: 4 passes of 32 rows through lbuf, dense stores ----
    #pragma unroll
    for (int p = 0; p < 4; ++p) {
        if (wm == p) {
            #pragma unroll
            for (int g = 0; g < 16; ++g) {
                const int   lr = (g & 3) + 8 * (g >> 2) + 4 * hi;
                const float mg = M[g], ig = I[g];
                #pragma unroll
                for (int t = 0; t < 8; ++t)
                    sm.lbuf[lr * 516 + wn * 256 + t * 32 + c32] =
                        __expf(fmaf(20.f, acc[t][g], -csqv[t]) - mg) * ig;
            }
        }
        __syncthreads();
        #pragma unroll
        for (int j = 0; j < 8; ++j) {
            const int f    = j * 512 + tid;     // 0..4095 float4 slots
            const int lrow = f >> 7;            // 0..31
            const int c4   = f & 127;
            float4    v    = *(const float4*)&sm.lbuf[lrow * 516 + c4 * 4];
            *(float4*)(out + (size_t)(row0 + p * 32 + lrow) * KC + c4 * 4) = v;
        }
        __syncthreads();
    }
}

extern "C" void kernel_launch(void* const* d_in, const int* in_sizes, int n_in,
                              void* d_out, int out_size, void* d_ws, size_t ws_size,
                              hipStream_t stream) {
    const float* x   = (const float*)d_in[0];
    const float* c   = (const float*)d_in[1];
    float*       out = (float*)d_out;

    unsigned short* bhi   = (unsigned short*)d_ws;                 // 256 KB
    unsigned short* blo   = bhi + (size_t)KCH * CHUNK_USH;         // 256 KB
    float*          csq10 = (float*)(blo + (size_t)KCH * CHUNK_USH);  // 2 KB

    prep_c<<<KC, 64, 0, stream>>>(c, bhi, blo, csq10);
    kmeans_mfma<<<NROWS / BM, 512, 0, stream>>>(x, bhi, blo, csq10, out);
}

// Round 10
// 118.841 us; speedup vs baseline: 1.0928x; 1.0928x over previous
//
#include <hip/hip_runtime.h>

// KMeans soft-assignment via bf16 hi/lo split MFMA (3 passes), fused softmax.
// logits = (2*x.c - ||c||^2)/T, T=0.1; ||x||^2 cancels in softmax.
// R20: MFMA ISSUE-ORDER A/B on R17 (best, 47.0us). R19 (32x32 shape)
// spilled (FETCH/WRITE inflation) -- dead end. Model audit: per-chunk/CU
// pipe demands sum to ~4.9k cyc but measured ~11.7k; the unexplained term
// is MFMA DEPENDENT-ACCUMULATION LATENCY: R17 issues same-accumulator
// MFMAs 2 apart (~9.7cyc) vs plausible ~16-20cyc result latency -> matrix
// pipe stalls ~2x inside every wave (matches MfmaUtil 20% = 3x ideal busy).
// Fix: 4 groups of 4 tiles; read bh[4]+bl[4] (8 ds_read_b128), then
// pass-major issue (8x ah*bh, 8x ah*bl, 8x al*bh) -> same-acc gap = 8
// issues (~39cyc). Per-element order h*h, h*l, l*h unchanged ->
// bit-identical (absmax 0.00390625). Everything else = R17 verbatim:
// counted vmcnt(4) -> s_barrier -> DMA-after-barrier, 1 barrier/chunk.
// x: [32768,256] f32, c: [512,256] f32, out: [32768,512] f32
#define NROWS 32768
#define KC 512
#define DDIM 256
#define BM 128
#define BK 32
#define KCH (DDIM / BK)        // 8 k-chunks
#define CHUNK_USH (KC * BK)    // 16384 ushorts = 32 KB per chunk table

typedef __attribute__((ext_vector_type(8))) short bf16x8;
typedef __attribute__((ext_vector_type(4))) float f32x4;

union U8 { unsigned short u[8]; bf16x8 v; };

__device__ __forceinline__ unsigned short f2bf(float f) {   // RNE f32->bf16
    union { float f; unsigned int u; } a; a.f = f;
    unsigned int r = a.u + 0x7fffu + ((a.u >> 16) & 1u);
    return (unsigned short)(r >> 16);
}
__device__ __forceinline__ float bf2f(unsigned short h) {
    union { unsigned int u; float f; } a; a.u = ((unsigned int)h) << 16;
    return a.f;
}
// async global->LDS, 16B/lane; LDS dst must be wave-uniform base + lane*16
__device__ __forceinline__ void ld16(const void* g, void* l) {
    __builtin_amdgcn_global_load_lds(
        (const __attribute__((address_space(1))) unsigned int*)g,
        (__attribute__((address_space(3))) unsigned int*)l, 16, 0, 0);
}

// ---- prep: c -> chunk-major, LDS-swizzle-baked bf16 hi/lo + csq10 ----
// octet (col n, quad q) at chunk offset (n*4 + (q ^ ((n>>1)&3)))*8 ushorts
__global__ __launch_bounds__(64) void prep_c(const float* __restrict__ c,
                                             unsigned short* __restrict__ bhi,
                                             unsigned short* __restrict__ blo,
                                             float* __restrict__ csq10) {
    const int n = blockIdx.x, lane = threadIdx.x;
    const int d0 = lane * 4;
    float4 v = ((const float4*)(c + (size_t)n * DDIM))[lane];
    float vv[4] = {v.x, v.y, v.z, v.w};
    unsigned short hh[4], ll[4];
    float ssq = 0.f;
    #pragma unroll
    for (int i = 0; i < 4; ++i) {
        ssq += vv[i] * vv[i];
        hh[i] = f2bf(vv[i]);
        ll[i] = f2bf(vv[i] - bf2f(hh[i]));
    }
    #pragma unroll
    for (int off = 32; off; off >>= 1) ssq += __shfl_xor(ssq, off);
    if (lane == 0) csq10[n] = 10.f * ssq;
    const int ks = d0 >> 5;
    const int q  = (d0 >> 3) & 3;
    const int s  = q ^ ((n >> 1) & 3);
    const size_t dst = (size_t)ks * CHUNK_USH + (n * 4 + s) * 8 + (d0 & 7);
    *(ushort4*)(bhi + dst) = make_ushort4(hh[0], hh[1], hh[2], hh[3]);
    *(ushort4*)(blo + dst) = make_ushort4(ll[0], ll[1], ll[2], ll[3]);
}

// ---- main: 256 blocks x 512 threads (8 waves = 4 M-groups x 2 N-halves) ----
union SmemU {
    struct { unsigned short Bh[2][CHUNK_USH], Bl[2][CHUNK_USH]; } k;  // 128 KB
    float lbuf[32 * 516];                                             // 66 KB overlay
};

__global__ __launch_bounds__(512, 2) void kmeans_mfma(
    const float* __restrict__ x, const unsigned short* __restrict__ bhi,
    const unsigned short* __restrict__ blo, const float* __restrict__ csq10,
    float* __restrict__ out) {
    __shared__ __align__(16) SmemU sm;
    __shared__ float red[2][2][BM];   // 2 KB

    const int tid  = threadIdx.x;
    const int w    = tid >> 6, lane = tid & 63;
    const int wm   = w >> 1, wn = w & 1;
    const int cc   = lane & 15, q = lane >> 4;
    const int row0 = blockIdx.x * BM;

    f32x4 acc[2][16];
    #pragma unroll
    for (int mt = 0; mt < 2; ++mt)
        #pragma unroll
        for (int t = 0; t < 16; ++t) acc[mt][t] = (f32x4){0.f, 0.f, 0.f, 0.f};

    // A: lane owns rows (row0 + wm*32 + mt*16 + cc), k-octet q*8 per chunk
    const float* xA0 = x + (size_t)(row0 + wm * 32 + cc) * DDIM + q * 8;
    const float* xA1 = xA0 + (size_t)16 * DDIM;
    // B fragment offset within staged chunk
    const int sF = q ^ ((cc >> 1) & 3);
    const int bF = (4 * cc + sF) * 8;       // + (wn*16+t)*512
    // DMA slots: wave w, j=0..3 -> 1 KB segment (w*4+j)*512 ushorts
    const int dmaOff = (w * 4) * 512;

    // ---- prologue: issue A(0), then DMA chunk 0 -> buf 0 (no barrier yet) ----
    float4 c00 = *(const float4*)xA0;
    float4 c01 = *(const float4*)(xA0 + 4);
    float4 c10 = *(const float4*)xA1;
    float4 c11 = *(const float4*)(xA1 + 4);
    #pragma unroll
    for (int j = 0; j < 4; ++j) {
        const int o = dmaOff + j * 512;
        ld16(bhi + o + lane * 8, &sm.k.Bh[0][o]);
        ld16(blo + o + lane * 8, &sm.k.Bl[0][o]);
    }

    #pragma unroll
    for (int ks = 0; ks < KCH; ++ks) {
        const int pp = ks & 1;
        // convert A(ks): compiler inserts a COUNTED vmcnt for these regs
        // (DMA(ks)'s 8 ops are younger -> stay in flight)
        bf16x8 ah[2], al[2];
        {
            float v0[8] = {c00.x, c00.y, c00.z, c00.w, c01.x, c01.y, c01.z, c01.w};
            float v1[8] = {c10.x, c10.y, c10.z, c10.w, c11.x, c11.y, c11.z, c11.w};
            U8 H0, L0, H1, L1;
            #pragma unroll
            for (int e = 0; e < 8; ++e) {
                H0.u[e] = f2bf(v0[e]); L0.u[e] = f2bf(v0[e] - bf2f(H0.u[e]));
                H1.u[e] = f2bf(v1[e]); L1.u[e] = f2bf(v1[e] - bf2f(H1.u[e]));
            }
            ah[0] = H0.v; al[0] = L0.v; ah[1] = H1.v; al[1] = L1.v;
        }
        // issue A(ks+1) raw (youngest; stays in flight across the barrier)
        float4 n00, n01, n10, n11;
        if (ks < KCH - 1) {
            const int kn = (ks + 1) * BK;
            n00 = *(const float4*)(xA0 + kn);
            n01 = *(const float4*)(xA0 + kn + 4);
            n10 = *(const float4*)(xA1 + kn);
            n11 = *(const float4*)(xA1 + kn + 4);
        }
        __builtin_amdgcn_sched_barrier(0);
        // counted wait: DMA(ks) complete; A(ks+1) (4 youngest) stays in flight.
        if (ks < KCH - 1) {
            asm volatile("s_waitcnt vmcnt(4)" ::: "memory");
        } else {
            asm volatile("s_waitcnt vmcnt(0)" ::: "memory");
        }
        __builtin_amdgcn_s_barrier();
        __builtin_amdgcn_sched_barrier(0);
        // issue DMA(ks+1) into the other slot (safe only post-barrier:
        // chunk ks-1's readers consumed that slot before this barrier)
        if (ks < KCH - 1) {
            const size_t cb = (size_t)(ks + 1) * CHUNK_USH;
            #pragma unroll
            for (int j = 0; j < 4; ++j) {
                const int o = dmaOff + j * 512;
                ld16(bhi + cb + o + lane * 8, &sm.k.Bh[1 - pp][o]);
                ld16(blo + cb + o + lane * 8, &sm.k.Bl[1 - pp][o]);
            }
        }
        // MFMA phase: 4 groups of 4 tiles; pass-major within group.
        // Same-accumulator issue gap = 8 MFMAs (~39cyc) vs R17's 2 (~10cyc).
        #pragma unroll
        for (int grp = 0; grp < 4; ++grp) {
            bf16x8 bh[4], bl[4];
            #pragma unroll
            for (int tt = 0; tt < 4; ++tt) {
                const int bo = (wn * 16 + grp * 4 + tt) * 512 + bF;
                bh[tt] = *(const bf16x8*)&sm.k.Bh[pp][bo];
                bl[tt] = *(const bf16x8*)&sm.k.Bl[pp][bo];
            }
            #pragma unroll
            for (int tt = 0; tt < 4; ++tt) {
                const int t = grp * 4 + tt;
                acc[0][t] = __builtin_amdgcn_mfma_f32_16x16x32_bf16(ah[0], bh[tt], acc[0][t], 0, 0, 0);
                acc[1][t] = __builtin_amdgcn_mfma_f32_16x16x32_bf16(ah[1], bh[tt], acc[1][t], 0, 0, 0);
            }
            #pragma unroll
            for (int tt = 0; tt < 4; ++tt) {
                const int t = grp * 4 + tt;
                acc[0][t] = __builtin_amdgcn_mfma_f32_16x16x32_bf16(ah[0], bl[tt], acc[0][t], 0, 0, 0);
                acc[1][t] = __builtin_amdgcn_mfma_f32_16x16x32_bf16(ah[1], bl[tt], acc[1][t], 0, 0, 0);
            }
            #pragma unroll
            for (int tt = 0; tt < 4; ++tt) {
                const int t = grp * 4 + tt;
                acc[0][t] = __builtin_amdgcn_mfma_f32_16x16x32_bf16(al[0], bh[tt], acc[0][t], 0, 0, 0);
                acc[1][t] = __builtin_amdgcn_mfma_f32_16x16x32_bf16(al[1], bh[tt], acc[1][t], 0, 0, 0);
            }
        }
        c00 = n00; c01 = n01; c10 = n10; c11 = n11;
    }

    // ---- softmax stats: reduce over t, then cc-lanes, then wn pair via LDS ----
    float csqv[16];
    #pragma unroll
    for (int t = 0; t < 16; ++t) csqv[t] = csq10[wn * 256 + t * 16 + cc];
    const int rb = wm * 32 + q * 4;   // + mt*16 + g
    float M[2][4], I[2][4];
    #pragma unroll
    for (int mt = 0; mt < 2; ++mt)
        #pragma unroll
        for (int g = 0; g < 4; ++g) {
            float pm = -1e30f;
            #pragma unroll
            for (int t = 0; t < 16; ++t) pm = fmaxf(pm, 20.f * acc[mt][t][g] - csqv[t]);
            #pragma unroll
            for (int off = 1; off < 16; off <<= 1) pm = fmaxf(pm, __shfl_xor(pm, off));
            if (cc == 0) red[0][wn][rb + mt * 16 + g] = pm;
            M[mt][g] = pm;
        }
    __syncthreads();
    #pragma unroll
    for (int mt = 0; mt < 2; ++mt)
        #pragma unroll
        for (int g = 0; g < 4; ++g) {
            M[mt][g] = fmaxf(M[mt][g], red[0][1 - wn][rb + mt * 16 + g]);
            float ps = 0.f;
            #pragma unroll
            for (int t = 0; t < 16; ++t) ps += __expf(20.f * acc[mt][t][g] - csqv[t] - M[mt][g]);
            #pragma unroll
            for (int off = 1; off < 16; off <<= 1) ps += __shfl_xor(ps, off);
            if (cc == 0) red[1][wn][rb + mt * 16 + g] = ps;
        }
    __syncthreads();
    #pragma unroll
    for (int mt = 0; mt < 2; ++mt)
        #pragma unroll
        for (int g = 0; g < 4; ++g)
            I[mt][g] = 1.f / (red[1][0][rb + mt * 16 + g] + red[1][1][rb + mt * 16 + g]);

    // ---- transpose epilogue: 4 passes of 32 rows through lbuf, dense stores ----
    #pragma unroll
    for (int p = 0; p < 4; ++p) {
        if (wm == p) {
            #pragma unroll
            for (int mt = 0; mt < 2; ++mt)
                #pragma unroll
                for (int g = 0; g < 4; ++g) {
                    const int   lr = mt * 16 + q * 4 + g;
                    const float mg = M[mt][g], ig = I[mt][g];
                    #pragma unroll
                    for (int t = 0; t < 16; ++t)
                        sm.lbuf[lr * 516 + wn * 256 + t * 16 + cc] =
                            __expf(20.f * acc[mt][t][g] - csqv[t] - mg) * ig;
                }
        }
        __syncthreads();
        #pragma unroll
        for (int j = 0; j < 8; ++j) {
            const int f    = j * 512 + tid;     // 0..4095 float4 slots
            const int lrow = f >> 7;            // 0..31
            const int c4   = f & 127;
            float4    v    = *(const float4*)&sm.lbuf[lrow * 516 + c4 * 4];
            *(float4*)(out + (size_t)(row0 + p * 32 + lrow) * KC + c4 * 4) = v;
        }
        __syncthreads();
    }
}

extern "C" void kernel_launch(void* const* d_in, const int* in_sizes, int n_in,
                              void* d_out, int out_size, void* d_ws, size_t ws_size,
                              hipStream_t stream) {
    const float* x   = (const float*)d_in[0];
    const float* c   = (const float*)d_in[1];
    float*       out = (float*)d_out;

    unsigned short* bhi   = (unsigned short*)d_ws;                 // 256 KB
    unsigned short* blo   = bhi + (size_t)KCH * CHUNK_USH;         // 256 KB
    float*          csq10 = (float*)(blo + (size_t)KCH * CHUNK_USH);  // 2 KB

    prep_c<<<KC, 64, 0, stream>>>(c, bhi, blo, csq10);
    kmeans_mfma<<<NROWS / BM, 512, 0, stream>>>(x, bhi, blo, csq10, out);
}